// Round 16
// baseline (629.175 us; speedup 1.0000x reference)
//
#include <hip/hip_runtime.h>

typedef __attribute__((ext_vector_type(4))) float f32x4;
typedef __attribute__((ext_vector_type(4))) unsigned int u32x4;
typedef __attribute__((ext_vector_type(8))) _Float16 half8;
typedef __attribute__((ext_vector_type(2))) _Float16 half2v;

__device__ inline f32x4 mfma_fp16(half8 a, half8 b, f32x4 c) {
  return __builtin_amdgcn_mfma_f32_16x16x32_f16(a, b, c, 0, 0, 0);
}

// XOR-swizzled element index, [rows][64 cols] fp16 tile (row stride 128B).
__device__ inline int kva(int row, int colbyte) {
  return ((row * 128 + colbyte) ^ ((row & 7) << 4)) >> 1;
}

// async global->LDS, 16B/lane; LDS dest = wave-uniform base + lane*16 (linear).
__device__ inline void gload16(const _Float16* g, _Float16* l) {
  __builtin_amdgcn_global_load_lds(
      (const __attribute__((address_space(1))) void*)g,
      (__attribute__((address_space(3))) void*)l, 16, 0, 0);
}

// All 4 weight matrices (K x N fp32) -> transposed fp16 hi/lo planes (N x K).
// lo = UNSCALED residual.
__global__ __launch_bounds__(256) void wsplit4_kernel(
    const float* __restrict__ Wq, const float* __restrict__ Wk,
    const float* __restrict__ Wv, const float* __restrict__ Wo,
    _Float16* __restrict__ Whi, _Float16* __restrict__ Wlo) {
  int w = blockIdx.y;
  const float* W = (w == 0) ? Wq : (w == 1) ? Wk : (w == 2) ? Wv : Wo;
  int i = blockIdx.x * 256 + threadIdx.x;
  int k = i / 768, n = i % 768;
  float v = W[i];
  _Float16 h = (_Float16)v;
  Whi[w * 589824 + n * 768 + k] = h;
  Wlo[w * 589824 + n * 768 + k] = (_Float16)(v - (float)h);
}

__device__ inline void asplit_body(const float* __restrict__ A,
                                   _Float16* __restrict__ Ahi,
                                   _Float16* __restrict__ Alo, int i) {
  f32x4 x0 = *(const f32x4*)(A + i);
  f32x4 x1 = *(const f32x4*)(A + i + 4);
  half8 vh, vl;
#pragma unroll
  for (int j = 0; j < 4; ++j) {
    _Float16 h0 = (_Float16)x0[j];
    vh[j] = h0; vl[j] = (_Float16)(x0[j] - (float)h0);
    _Float16 h1 = (_Float16)x1[j];
    vh[4 + j] = h1; vl[4 + j] = (_Float16)(x1[j] - (float)h1);
  }
  *(half8*)(Ahi + i) = vh;
  *(half8*)(Alo + i) = vl;
}

__global__ __launch_bounds__(256) void asplit_kernel(const float* __restrict__ A,
                                                     _Float16* __restrict__ Ahi,
                                                     _Float16* __restrict__ Alo) {
  asplit_body(A, Ahi, Alo, (blockIdx.x * 256 + threadIdx.x) * 8);
}

__global__ __launch_bounds__(256) void asplit3_kernel(
    const float* __restrict__ Aq, const float* __restrict__ Ak,
    const float* __restrict__ Av,
    _Float16* __restrict__ Aqh, _Float16* __restrict__ Aql,
    _Float16* __restrict__ Akh, _Float16* __restrict__ Akl,
    _Float16* __restrict__ Avh, _Float16* __restrict__ Avl) {
  int w = blockIdx.y;
  const float* A = (w == 0) ? Aq : (w == 1) ? Ak : Av;
  _Float16* H = (w == 0) ? Aqh : (w == 1) ? Akh : Avh;
  _Float16* L = (w == 0) ? Aql : (w == 1) ? Akl : Avl;
  asplit_body(A, H, L, (blockIdx.x * 256 + threadIdx.x) * 8);
}

// Vt plane base (in elements) for (b, head). Per-b size = 3,670,016 elems.
__device__ inline int vt_base(int b, int h) {
  int base = b * 3670016;
  if (h < 4)      base += h * 524288;
  else if (h < 8) base += 2097152 + (h - 4) * 262144;
  else            base += 3145728 + (h - 8) * 131072;
  return base;
}

// High-precision GEMM core (R13 form — BK=64, (512,2)).
__device__ __forceinline__ void gemm3_core(
    const _Float16* __restrict__ Ahi, const _Float16* __restrict__ Alo,
    const _Float16* __restrict__ Bhi, const _Float16* __restrict__ Blo,
    const float* __restrict__ bias, _Float16* __restrict__ Chi,
    _Float16* __restrict__ Clo, int mode, int m0, int n0,
    _Float16* Ah, _Float16* Al, _Float16* Bh, _Float16* Bl) {
  int tid = threadIdx.x;
  int lane = tid & 63, wid = tid >> 6;
  int wm = wid >> 1, wn = wid & 1;
  int lg = lane >> 4, lc = lane & 15;

  f32x4 acc[2][4] = {};

  size_t sA[2], sB[2];
  int ldst[2];
#pragma unroll
  for (int c = 0; c < 2; ++c) {
    int idxv = c * 512 + tid;
    int m = idxv >> 3;
    int ke = ((idxv & 7) << 3) ^ ((m & 7) << 3);
    sA[c] = (size_t)(m0 + m) * 768 + ke;
    sB[c] = (size_t)(n0 + m) * 768 + ke;
    ldst[c] = (c * 512 + wid * 64) * 8;
  }

  for (int k0 = 0; k0 < 768; k0 += 64) {
    __syncthreads();
#pragma unroll
    for (int c = 0; c < 2; ++c) {
      gload16(Ahi + sA[c] + k0, Ah + ldst[c]);
      gload16(Alo + sA[c] + k0, Al + ldst[c]);
      gload16(Bhi + sB[c] + k0, Bh + ldst[c]);
      gload16(Blo + sB[c] + k0, Bl + ldst[c]);
    }
    __syncthreads();

#pragma unroll
    for (int ks = 0; ks < 2; ++ks) {
      half8 ah[2], al[2], bh[4], bl[4];
#pragma unroll
      for (int mt = 0; mt < 2; ++mt) {
        int ro = kva(wm * 32 + mt * 16 + lc, ks * 64 + (lg << 4));
        ah[mt] = *(half8*)(&Ah[ro]);
        al[mt] = *(half8*)(&Al[ro]);
      }
#pragma unroll
      for (int nf = 0; nf < 4; ++nf) {
        int ro = kva(wn * 64 + nf * 16 + lc, ks * 64 + (lg << 4));
        bh[nf] = *(half8*)(&Bh[ro]);
        bl[nf] = *(half8*)(&Bl[ro]);
      }
#pragma unroll
      for (int mt = 0; mt < 2; ++mt)
#pragma unroll
        for (int nf = 0; nf < 4; ++nf) {
          acc[mt][nf] = mfma_fp16(al[mt], bh[nf], acc[mt][nf]);
          acc[mt][nf] = mfma_fp16(ah[mt], bl[nf], acc[mt][nf]);
          acc[mt][nf] = mfma_fp16(ah[mt], bh[nf], acc[mt][nf]);
        }
    }
  }

#pragma unroll
  for (int mt = 0; mt < 2; ++mt)
#pragma unroll
    for (int nf = 0; nf < 4; ++nf) {
      int col = n0 + wn * 64 + nf * 16 + lc;
      int row0 = m0 + wm * 32 + mt * 16 + (lg << 2);
      float bv = bias[col];
#pragma unroll
      for (int rr = 0; rr < 4; ++rr) {
        int row = row0 + rr;
        float v = acc[mt][nf][rr] + bv;
        _Float16 h = (_Float16)v;
        _Float16 l = (_Float16)(v - (float)h);
        if (mode == 0) {
          Chi[(size_t)row * 768 + col] = h;
          Clo[(size_t)row * 768 + col] = l;
        } else {
          int b = row >> 13, pos = row & 8191;
          int hh = col >> 6, d = col & 63;
          int g = hh >> 2;
          int rdil = 1 << g;
          if ((pos & (rdil - 1)) == g) {
            int t = (pos - g) >> g;
            int Ng = 8192 >> g;
            Chi[vt_base(b, hh) + d * Ng + t] = h;
            Clo[vt_base(b, hh) + d * Ng + t] = l;
          }
        }
      }
    }
}

// fallback: one projection per launch (2D grid, no swizzle)
__global__ __launch_bounds__(512, 2) void gemm3_kernel(
    const _Float16* __restrict__ Ahi, const _Float16* __restrict__ Alo,
    const _Float16* __restrict__ Bhi, const _Float16* __restrict__ Blo,
    const float* __restrict__ bias,
    _Float16* __restrict__ Chi, _Float16* __restrict__ Clo, int mode) {
  __shared__ _Float16 Ah[128 * 64], Al[128 * 64], Bh[128 * 64], Bl[128 * 64];
  gemm3_core(Ahi, Alo, Bhi, Blo, bias, Chi, Clo, mode,
             blockIdx.y * 128, blockIdx.x * 128, Ah, Al, Bh, Bl);
}

// batched: all three projections, 1D grid 2304, XCD-chunked (288/XCD).
__global__ __launch_bounds__(512, 2) void gemm3b_kernel(
    const _Float16* __restrict__ Aqh, const _Float16* __restrict__ Aql,
    const _Float16* __restrict__ Akh, const _Float16* __restrict__ Akl,
    const _Float16* __restrict__ Avh, const _Float16* __restrict__ Avl,
    const _Float16* __restrict__ Wsh, const _Float16* __restrict__ Wsl,
    const float* __restrict__ bq, const float* __restrict__ bk,
    const float* __restrict__ bv,
    _Float16* __restrict__ Qhb, _Float16* __restrict__ Qlb,
    _Float16* __restrict__ Khb, _Float16* __restrict__ Klb,
    _Float16* __restrict__ Vth, _Float16* __restrict__ Vtl) {
  __shared__ _Float16 Ah[128 * 64], Al[128 * 64], Bh[128 * 64], Bl[128 * 64];
  int orig = blockIdx.x;                    // 0..2303, nwg%8==0
  int wg = (orig & 7) * 288 + (orig >> 3);  // bijective XCD chunking
  int sec = wg / 768, rem = wg % 768;
  int m0 = (rem / 6) * 128, n0 = (rem % 6) * 128;
  const _Float16* Ahi = (sec == 0) ? Aqh : (sec == 1) ? Akh : Avh;
  const _Float16* Alo = (sec == 0) ? Aql : (sec == 1) ? Akl : Avl;
  const float* bias = (sec == 0) ? bq : (sec == 1) ? bk : bv;
  _Float16* Chi = (sec == 0) ? Qhb : (sec == 1) ? Khb : Vth;
  _Float16* Clo = (sec == 0) ? Qlb : (sec == 1) ? Klb : Vtl;
  gemm3_core(Ahi, Alo, Wsh + sec * 589824, Wsl + sec * 589824, bias,
             Chi, Clo, (sec == 2) ? 1 : 0, m0, n0, Ah, Al, Bh, Bl);
}

// Output projection: C(fp32) = A(fp16) @ Wt^T + bias. 1D grid 768, XCD-chunked.
__global__ __launch_bounds__(256, 4) void gemm1_kernel(
    const _Float16* __restrict__ A, const _Float16* __restrict__ Bt,
    const float* __restrict__ bias, float* __restrict__ C) {
  __shared__ _Float16 As[128 * 64];
  __shared__ _Float16 Bs[128 * 64];
  int orig = blockIdx.x;                    // 0..767
  int wg = (orig & 7) * 96 + (orig >> 3);   // bijective XCD chunking
  int m0 = (wg / 6) * 128, n0 = (wg % 6) * 128;
  int tid = threadIdx.x;
  int lane = tid & 63, wid = tid >> 6;
  int wm = wid >> 1, wn = wid & 1;
  int lg = lane >> 4, lc = lane & 15;

  f32x4 acc[4][4] = {};

  size_t sA[4], sB[4];
  int ldst[4];
#pragma unroll
  for (int c = 0; c < 4; ++c) {
    int idxv = c * 256 + tid;
    int m = idxv >> 3;
    int ke = ((idxv & 7) << 3) ^ ((m & 7) << 3);
    sA[c] = (size_t)(m0 + m) * 768 + ke;
    sB[c] = (size_t)(n0 + m) * 768 + ke;
    ldst[c] = (c * 256 + wid * 64) * 8;
  }

  for (int k0 = 0; k0 < 768; k0 += 64) {
    __syncthreads();
#pragma unroll
    for (int c = 0; c < 4; ++c) {
      gload16(A + sA[c] + k0, As + ldst[c]);
      gload16(Bt + sB[c] + k0, Bs + ldst[c]);
    }
    __syncthreads();
#pragma unroll
    for (int ks = 0; ks < 2; ++ks) {
      half8 af[4], bf[4];
#pragma unroll
      for (int mt = 0; mt < 4; ++mt)
        af[mt] = *(half8*)(&As[kva(wm * 64 + mt * 16 + lc, ks * 64 + (lg << 4))]);
#pragma unroll
      for (int nf = 0; nf < 4; ++nf)
        bf[nf] = *(half8*)(&Bs[kva(wn * 64 + nf * 16 + lc, ks * 64 + (lg << 4))]);
#pragma unroll
      for (int mt = 0; mt < 4; ++mt)
#pragma unroll
        for (int nf = 0; nf < 4; ++nf)
          acc[mt][nf] = mfma_fp16(af[mt], bf[nf], acc[mt][nf]);
    }
  }

#pragma unroll
  for (int mt = 0; mt < 4; ++mt)
#pragma unroll
    for (int nf = 0; nf < 4; ++nf) {
      int col = n0 + wn * 64 + nf * 16 + lc;
      int row0 = m0 + wm * 64 + mt * 16 + (lg << 2);
      float bv = bias[col];
#pragma unroll
      for (int rr = 0; rr < 4; ++rr)
        C[(size_t)(row0 + rr) * 768 + col] = acc[mt][nf][rr] + bv;
    }
}

// Single-pass dilated flash attention, fp16-pair precision, merged accumulator.
// 4 waves x 32 q rows: each K/V LDS fragment feeds TWO q-tiles (A: q0+lc,
// B: q0+16+lc) -> LDS reads per unit work halved (R15 analysis: 80% LDS-bound).
// exp/pack fused per-nf (p needs no row max/normalize) to cap VGPR; staging
// via gload_lds (drain at barrier, gemm3-style). Per-q math chains identical
// to R15 -> absmax must stay bit-identical.
__global__ __launch_bounds__(256, 3) void attn_kernel(
    const _Float16* __restrict__ Qh, const _Float16* __restrict__ Ql,
    const _Float16* __restrict__ Kh, const _Float16* __restrict__ Kl,
    const _Float16* __restrict__ Vth, const _Float16* __restrict__ Vtl,
    _Float16* __restrict__ Xh, float* __restrict__ partial) {
  __shared__ _Float16 Ksh[64 * 64], Ksl[64 * 64];   // XOR-swizzled, stride 64
  __shared__ _Float16 Vsh[64 * 64], Vsl[64 * 64];
  __shared__ float wred[4][64];

  int bid = blockIdx.x;
  int xcd = bid & 7, idx = bid >> 3;
  int u_glob = xcd * 7 + (idx >> 4);
  int qblk = idx & 15;
  int g = (u_glob < 32) ? 0 : (u_glob < 48) ? 1 : 2;
  int u = (g == 0) ? u_glob : (g == 1) ? u_glob - 32 : u_glob - 48;
  int nsegs = 4 >> g;
  int b = u / (nsegs * 4), rem = u % (nsegs * 4);
  int nseg = rem >> 2, hg = rem & 3;
  int head = g * 4 + hg;
  int s = 2048 << g, r = 1 << g, off = g;
  int Ng = 8192 >> g;
  int tbase = nseg * 2048;
  int vbase = vt_base(b, head);

  int tid = threadIdx.x, lane = tid & 63, wid = tid >> 6;  // wid 0..3
  int lg = lane >> 4, lc = lane & 15;

  int q0 = qblk * 128 + wid * 32;
  half8 qAh[2], qAl[2], qBh[2], qBl[2];
  {
    int posA = nseg * s + off + (q0 + lc) * r;
    int posB = nseg * s + off + (q0 + 16 + lc) * r;
    size_t roA = (size_t)(b * 8192 + posA) * 768 + head * 64;
    size_t roB = (size_t)(b * 8192 + posB) * 768 + head * 64;
#pragma unroll
    for (int ks = 0; ks < 2; ++ks) {
      qAh[ks] = *(const half8*)(Qh + roA + ks * 32 + (lg << 3));
      qAl[ks] = *(const half8*)(Ql + roA + ks * 32 + (lg << 3));
      qBh[ks] = *(const half8*)(Qh + roB + ks * 32 + (lg << 3));
      qBl[ks] = *(const half8*)(Ql + roB + ks * 32 + (lg << 3));
    }
  }

  // staging: pass c covers rows c*32 + wid*8 + (lane>>3); 16B per lane.
  // source column pre-XORed so linear gload_lds deposit realizes kva layout.
  int krl = (lane >> 3);                 // 0..7
  int ke = (((lane & 7) ^ krl) << 3);    // pre-swizzled elem col
  size_t kro[2], vro[2];
  int ldk[2];
#pragma unroll
  for (int c = 0; c < 2; ++c) {
    int kr = c * 32 + wid * 8 + krl;
    kro[c] = (size_t)(b * 8192 + nseg * s + off + kr * r) * 768 + head * 64 + ke;
    vro[c] = (size_t)vbase + (size_t)kr * Ng + tbase + ke;
    ldk[c] = c * 2048 + wid * 512;       // wave-uniform element base
  }
  const size_t kstep = (size_t)64 * r * 768;

  f32x4 accA[4] = {};
  f32x4 accB[4] = {};
  float lsumA = 0.f, lsumB = 0.f;

  const int sl0 = ((lane & 16) << 1) + lc;
  const int sl1 = sl0 + 16;
  const bool hiSel = (lane & 32) != 0;

  for (int kt = 0; kt < 32; ++kt) {
    __syncthreads();                 // readers done with previous tile
#pragma unroll
    for (int c = 0; c < 2; ++c) {
      gload16(Kh + kro[c], Ksh + ldk[c]);
      gload16(Kl + kro[c], Ksl + ldk[c]);
      gload16(Vth + vro[c], Vsh + ldk[c]);
      gload16(Vtl + vro[c], Vsl + ldk[c]);
      kro[c] += kstep;
      vro[c] += 64;
    }
    __syncthreads();                 // vmcnt drained -> tile ready

    // S^T = K·Q for both q-tiles; exp+pack fused per nf (no full sc array)
    unsigned int pkA[4][2], pkB[4][2];
#pragma unroll
    for (int nf = 0; nf < 4; ++nf) {
      half8 kh[2], kl[2];
#pragma unroll
      for (int ks = 0; ks < 2; ++ks) {
        int ro = kva(nf * 16 + lc, ks * 64 + (lg << 4));
        kh[ks] = *(half8*)(&Ksh[ro]);
        kl[ks] = *(half8*)(&Ksl[ro]);
      }
      f32x4 tA = {}, tB = {};
#pragma unroll
      for (int ks = 0; ks < 2; ++ks) {
        tA = mfma_fp16(kl[ks], qAh[ks], tA);
        tA = mfma_fp16(kh[ks], qAl[ks], tA);
        tB = mfma_fp16(kl[ks], qBh[ks], tB);
        tB = mfma_fp16(kh[ks], qBl[ks], tB);
      }
#pragma unroll
      for (int ks = 0; ks < 2; ++ks) {
        tA = mfma_fp16(kh[ks], qAh[ks], tA);
        tB = mfma_fp16(kh[ks], qBh[ks], tB);
      }
      _Float16 hA[4], hB[4];
#pragma unroll
      for (int rr = 0; rr < 4; ++rr) {
        float pA = __expf(tA[rr] * 0.125f);
        float pB = __expf(tB[rr] * 0.125f);
        hA[rr] = (_Float16)pA; lsumA += (float)hA[rr];
        hB[rr] = (_Float16)pB; lsumB += (float)hB[rr];
      }
      half2v a01 = {hA[0], hA[1]}, a23 = {hA[2], hA[3]};
      half2v b01 = {hB[0], hB[1]}, b23 = {hB[2], hB[3]};
      pkA[nf][0] = __builtin_bit_cast(unsigned int, a01);
      pkA[nf][1] = __builtin_bit_cast(unsigned int, a23);
      pkB[nf][0] = __builtin_bit_cast(unsigned int, b01);
      pkB[nf][1] = __builtin_bit_cast(unsigned int, b23);
    }

    // PV: V fragments read ONCE, feed both tiles
#pragma unroll
    for (int ks2 = 0; ks2 < 2; ++ks2) {
      int nfA = 2 * ks2, nfB = 2 * ks2 + 1;
      unsigned int aA0 = __shfl(pkA[nfA][0], sl0, 64);
      unsigned int aB0 = __shfl(pkA[nfB][0], sl0, 64);
      unsigned int aA1 = __shfl(pkA[nfA][1], sl0, 64);
      unsigned int aB1 = __shfl(pkA[nfB][1], sl0, 64);
      unsigned int aA2 = __shfl(pkA[nfA][0], sl1, 64);
      unsigned int aB2 = __shfl(pkA[nfB][0], sl1, 64);
      unsigned int aA3 = __shfl(pkA[nfA][1], sl1, 64);
      unsigned int aB3 = __shfl(pkA[nfB][1], sl1, 64);
      u32x4 pwA;
      pwA[0] = hiSel ? aB0 : aA0;
      pwA[1] = hiSel ? aB1 : aA1;
      pwA[2] = hiSel ? aB2 : aA2;
      pwA[3] = hiSel ? aB3 : aA3;
      half8 paA = __builtin_bit_cast(half8, pwA);

      unsigned int bA0 = __shfl(pkB[nfA][0], sl0, 64);
      unsigned int bB0 = __shfl(pkB[nfB][0], sl0, 64);
      unsigned int bA1 = __shfl(pkB[nfA][1], sl0, 64);
      unsigned int bB1 = __shfl(pkB[nfB][1], sl0, 64);
      unsigned int bA2 = __shfl(pkB[nfA][0], sl1, 64);
      unsigned int bB2 = __shfl(pkB[nfB][0], sl1, 64);
      unsigned int bA3 = __shfl(pkB[nfA][1], sl1, 64);
      unsigned int bB3 = __shfl(pkB[nfB][1], sl1, 64);
      u32x4 pwB;
      pwB[0] = hiSel ? bB0 : bA0;
      pwB[1] = hiSel ? bB1 : bA1;
      pwB[2] = hiSel ? bB2 : bA2;
      pwB[3] = hiSel ? bB3 : bA3;
      half8 paB = __builtin_bit_cast(half8, pwB);

#pragma unroll
      for (int nf = 0; nf < 4; ++nf) {
        int ro = kva(nf * 16 + lc, ks2 * 64 + (lg << 4));
        half8 vh = *(half8*)(&Vsh[ro]);
        half8 vl = *(half8*)(&Vsl[ro]);
        accA[nf] = mfma_fp16(paA, vl, accA[nf]);
        accA[nf] = mfma_fp16(paA, vh, accA[nf]);
        accB[nf] = mfma_fp16(paB, vl, accB[nf]);
        accB[nf] = mfma_fp16(paB, vh, accB[nf]);
      }
    }
  }

  // row sums: combine the 4 lg groups per tile
  lsumA += __shfl_xor(lsumA, 16, 64);
  lsumA += __shfl_xor(lsumA, 32, 64);
  lsumB += __shfl_xor(lsumB, 16, 64);
  lsumB += __shfl_xor(lsumB, 32, 64);
  float invA = 1.0f / lsumA;
  float invB = 1.0f / lsumB;

  // epilogue: store fp16 X for both tiles; column sums from ROUNDED values
  float cs[4] = {};
#pragma unroll
  for (int rr = 0; rr < 4; ++rr) {
    int qi = ((lane >> 4) & 3) * 4 + rr;
    float invqA = __shfl(invA, (lane & 48) + qi, 64);
    float invqB = __shfl(invB, (lane & 48) + qi, 64);
    int posA = nseg * s + off + (q0 + qi) * r;
    int posB = nseg * s + off + (q0 + 16 + qi) * r;
    _Float16* xrA = Xh + (size_t)(b * 8192 + posA) * 768 + head * 64;
    _Float16* xrB = Xh + (size_t)(b * 8192 + posB) * 768 + head * 64;
#pragma unroll
    for (int nf = 0; nf < 4; ++nf) {
      _Float16 hxA = (_Float16)(accA[nf][rr] * invqA);
      _Float16 hxB = (_Float16)(accB[nf][rr] * invqB);
      xrA[nf * 16 + lc] = hxA;
      xrB[nf * 16 + lc] = hxB;
      cs[nf] += (float)hxA + (float)hxB;
    }
  }
#pragma unroll
  for (int nf = 0; nf < 4; ++nf) {
    cs[nf] += __shfl_xor(cs[nf], 16, 64);
    cs[nf] += __shfl_xor(cs[nf], 32, 64);
    if (lane < 16) wred[wid][nf * 16 + lc] = cs[nf];
  }
  __syncthreads();
  if (tid < 64) {
    float w4 = wred[0][tid] + wred[1][tid] + wred[2][tid] + wred[3][tid];
    int slot = ((b * 12 + head) * 64 + nseg * 16 + qblk);
    partial[slot * 64 + tid] = w4;
  }
}

// div[b*768 + h*64 + d] = sum over this head's (nsegs*16) block partials
__global__ __launch_bounds__(256) void colsum2_kernel(const float* __restrict__ partial,
                                                      float* __restrict__ divbuf) {
  int i = blockIdx.x * 256 + threadIdx.x;  // 0..1535
  int b = i / 768, e = i % 768;
  int h = e >> 6, d = e & 63;
  int g = h >> 2;
  int nslots = 64 >> g;
  const float* src = partial + (size_t)((b * 12 + h) * 64) * 64 + d;
  float sacc = 0.f;
  for (int c = 0; c < nslots; ++c) sacc += src[c * 64];
  divbuf[i] = sacc;
}

// LayerNorm, wave-per-row: fp16 in/out, fuses /(div*3) + written-slot mask.
__global__ __launch_bounds__(256) void ln_kernel(const _Float16* __restrict__ Xh,
                                                 _Float16* __restrict__ Xln,
                                                 const float* __restrict__ divbuf,
                                                 const float* __restrict__ ln_w,
                                                 const float* __restrict__ ln_b) {
  int wid = threadIdx.x >> 6, lane = threadIdx.x & 63;
  int row = blockIdx.x * 4 + wid;
  int b = row >> 13, pos = row & 8191;
  float x[12];
  float s1 = 0.f, s2 = 0.f;
#pragma unroll
  for (int j = 0; j < 12; ++j) {
    int e = lane + 64 * j;
    int g = j >> 2;
    bool wr = (g == 0) || (g == 1 && (pos & 1) == 1) || (g == 2 && (pos & 3) == 2);
    float v = 0.f;
    if (wr) v = (float)Xh[(size_t)row * 768 + e] / (divbuf[b * 768 + e] * 3.0f);
    x[j] = v;
    s1 += v;
    s2 += v * v;
  }
#pragma unroll
  for (int msk = 1; msk < 64; msk <<= 1) {
    s1 += __shfl_xor(s1, msk, 64);
    s2 += __shfl_xor(s2, msk, 64);
  }
  float mean = s1 * (1.0f / 768.0f);
  float var = s2 * (1.0f / 768.0f) - mean * mean;
  float inv = rsqrtf(var + 1e-5f);
#pragma unroll
  for (int j = 0; j < 12; ++j) {
    int e = lane + 64 * j;
    Xln[(size_t)row * 768 + e] = (_Float16)((x[j] - mean) * inv * ln_w[e] + ln_b[e]);
  }
}

extern "C" void kernel_launch(void* const* d_in, const int* in_sizes, int n_in,
                              void* d_out, int out_size, void* d_ws, size_t ws_size,
                              hipStream_t stream) {
  const float* query = (const float*)d_in[0];
  const float* key   = (const float*)d_in[1];
  const float* value = (const float*)d_in[2];
  const float* Wq = (const float*)d_in[3];
  const float* bq = (const float*)d_in[4];
  const float* Wk = (const float*)d_in[5];
  const float* bk = (const float*)d_in[6];
  const float* Wv = (const float*)d_in[7];
  const float* bv = (const float*)d_in[8];
  const float* Wo = (const float*)d_in[9];
  const float* bo = (const float*)d_in[10];
  const float* ln_w = (const float*)d_in[11];
  const float* ln_b = (const float*)d_in[12];

  char* ws = (char*)d_ws;
  _Float16* Wsh = (_Float16*)ws; ws += (size_t)4 * 589824 * 2;
  _Float16* Wsl = (_Float16*)ws; ws += (size_t)4 * 589824 * 2;
  _Float16* Qhb = (_Float16*)ws; ws += (size_t)16384 * 768 * 2;
  _Float16* Qlb = (_Float16*)ws; ws += (size_t)16384 * 768 * 2;
  _Float16* Khb = (_Float16*)ws; ws += (size_t)16384 * 768 * 2;
  _Float16* Klb = (_Float16*)ws; ws += (size_t)16384 * 768 * 2;
  _Float16* Vth = (_Float16*)ws; ws += (size_t)7340032 * 2;
  _Float16* Vtl = (_Float16*)ws; ws += (size_t)7340032 * 2;
  char* Xregion = ws; ws += (size_t)16384 * 768 * 4;   // Xh + Xln (fp16 each)
  float* partial = (float*)ws; ws += (size_t)24 * 64 * 64 * 4;
  float* divbuf = (float*)ws; ws += 2 * 768 * 4;

  _Float16* Xh  = (_Float16*)Xregion;
  _Float16* Xln = Xh + (size_t)16384 * 768;
  _Float16* Aqh = (_Float16*)Xregion;
  _Float16* Aql = Aqh + (size_t)16384 * 768;

  size_t base_bytes = (size_t)(ws - (char*)d_ws);
  size_t extra = (size_t)4 * 16384 * 768 * 2;
  bool batched = ws_size >= base_bytes + extra;

  wsplit4_kernel<<<dim3(2304, 4), 256, 0, stream>>>(Wq, Wk, Wv, Wo, Wsh, Wsl);

  dim3 ggrid(6, 128);
  if (batched) {
    _Float16* Akh = (_Float16*)ws; ws += (size_t)16384 * 768 * 2;
    _Float16* Akl = (_Float16*)ws; ws += (size_t)16384 * 768 * 2;
    _Float16* Avh = (_Float16*)ws; ws += (size_t)16384 * 768 * 2;
    _Float16* Avl = (_Float16*)ws; ws += (size_t)16384 * 768 * 2;
    asplit3_kernel<<<dim3(6144, 3), 256, 0, stream>>>(query, key, value,
        Aqh, Aql, Akh, Akl, Avh, Avl);
    gemm3b_kernel<<<2304, 512, 0, stream>>>(
        Aqh, Aql, Akh, Akl, Avh, Avl, Wsh, Wsl, bq, bk, bv,
        Qhb, Qlb, Khb, Klb, Vth, Vtl);
  } else {
    asplit_kernel<<<6144, 256, 0, stream>>>(query, Aqh, Aql);
    gemm3_kernel<<<ggrid, 512, 0, stream>>>(Aqh, Aql, Wsh, Wsl, bq, Qhb, Qlb, 0);
    asplit_kernel<<<6144, 256, 0, stream>>>(key, Aqh, Aql);
    gemm3_kernel<<<ggrid, 512, 0, stream>>>(Aqh, Aql, Wsh + 589824, Wsl + 589824, bk, Khb, Klb, 0);
    asplit_kernel<<<6144, 256, 0, stream>>>(value, Aqh, Aql);
    gemm3_kernel<<<ggrid, 512, 0, stream>>>(Aqh, Aql, Wsh + 2 * 589824, Wsl + 2 * 589824, bv, Vth, Vtl, 1);
  }

  attn_kernel<<<896, 256, 0, stream>>>(Qhb, Qlb, Khb, Klb, Vth, Vtl, Xh, partial);

  colsum2_kernel<<<6, 256, 0, stream>>>(partial, divbuf);
  ln_kernel<<<4096, 256, 0, stream>>>(Xh, Xln, divbuf, ln_w, ln_b);

  gemm1_kernel<<<768, 256, 0, stream>>>(Xln, Wsh + 3 * 589824, bo, (float*)d_out);
}

// Round 17
// 617.815 us; speedup vs baseline: 1.0184x; 1.0184x over previous
//
#include <hip/hip_runtime.h>

typedef __attribute__((ext_vector_type(4))) float f32x4;
typedef __attribute__((ext_vector_type(4))) unsigned int u32x4;
typedef __attribute__((ext_vector_type(8))) _Float16 half8;
typedef __attribute__((ext_vector_type(2))) _Float16 half2v;

__device__ inline f32x4 mfma_fp16(half8 a, half8 b, f32x4 c) {
  return __builtin_amdgcn_mfma_f32_16x16x32_f16(a, b, c, 0, 0, 0);
}

// XOR-swizzled element index, [rows][64 cols] fp16 tile (row stride 128B).
__device__ inline int kva(int row, int colbyte) {
  return ((row * 128 + colbyte) ^ ((row & 7) << 4)) >> 1;
}

// async global->LDS, 16B/lane; LDS dest = wave-uniform base + lane*16 (linear).
__device__ inline void gload16(const _Float16* g, _Float16* l) {
  __builtin_amdgcn_global_load_lds(
      (const __attribute__((address_space(1))) void*)g,
      (__attribute__((address_space(3))) void*)l, 16, 0, 0);
}

// All 4 weight matrices (K x N fp32) -> transposed fp16 hi/lo planes (N x K).
// lo = UNSCALED residual.
__global__ __launch_bounds__(256) void wsplit4_kernel(
    const float* __restrict__ Wq, const float* __restrict__ Wk,
    const float* __restrict__ Wv, const float* __restrict__ Wo,
    _Float16* __restrict__ Whi, _Float16* __restrict__ Wlo) {
  int w = blockIdx.y;
  const float* W = (w == 0) ? Wq : (w == 1) ? Wk : (w == 2) ? Wv : Wo;
  int i = blockIdx.x * 256 + threadIdx.x;
  int k = i / 768, n = i % 768;
  float v = W[i];
  _Float16 h = (_Float16)v;
  Whi[w * 589824 + n * 768 + k] = h;
  Wlo[w * 589824 + n * 768 + k] = (_Float16)(v - (float)h);
}

__device__ inline void asplit_body(const float* __restrict__ A,
                                   _Float16* __restrict__ Ahi,
                                   _Float16* __restrict__ Alo, int i) {
  f32x4 x0 = *(const f32x4*)(A + i);
  f32x4 x1 = *(const f32x4*)(A + i + 4);
  half8 vh, vl;
#pragma unroll
  for (int j = 0; j < 4; ++j) {
    _Float16 h0 = (_Float16)x0[j];
    vh[j] = h0; vl[j] = (_Float16)(x0[j] - (float)h0);
    _Float16 h1 = (_Float16)x1[j];
    vh[4 + j] = h1; vl[4 + j] = (_Float16)(x1[j] - (float)h1);
  }
  *(half8*)(Ahi + i) = vh;
  *(half8*)(Alo + i) = vl;
}

__global__ __launch_bounds__(256) void asplit_kernel(const float* __restrict__ A,
                                                     _Float16* __restrict__ Ahi,
                                                     _Float16* __restrict__ Alo) {
  asplit_body(A, Ahi, Alo, (blockIdx.x * 256 + threadIdx.x) * 8);
}

__global__ __launch_bounds__(256) void asplit3_kernel(
    const float* __restrict__ Aq, const float* __restrict__ Ak,
    const float* __restrict__ Av,
    _Float16* __restrict__ Aqh, _Float16* __restrict__ Aql,
    _Float16* __restrict__ Akh, _Float16* __restrict__ Akl,
    _Float16* __restrict__ Avh, _Float16* __restrict__ Avl) {
  int w = blockIdx.y;
  const float* A = (w == 0) ? Aq : (w == 1) ? Ak : Av;
  _Float16* H = (w == 0) ? Aqh : (w == 1) ? Akh : Avh;
  _Float16* L = (w == 0) ? Aql : (w == 1) ? Akl : Avl;
  asplit_body(A, H, L, (blockIdx.x * 256 + threadIdx.x) * 8);
}

// Vt plane base (in elements) for (b, head). Per-b size = 3,670,016 elems.
__device__ inline int vt_base(int b, int h) {
  int base = b * 3670016;
  if (h < 4)      base += h * 524288;
  else if (h < 8) base += 2097152 + (h - 4) * 262144;
  else            base += 3145728 + (h - 8) * 131072;
  return base;
}

// High-precision GEMM core (R13 form — BK=64, (512,2)).
__device__ __forceinline__ void gemm3_core(
    const _Float16* __restrict__ Ahi, const _Float16* __restrict__ Alo,
    const _Float16* __restrict__ Bhi, const _Float16* __restrict__ Blo,
    const float* __restrict__ bias, _Float16* __restrict__ Chi,
    _Float16* __restrict__ Clo, int mode, int m0, int n0,
    _Float16* Ah, _Float16* Al, _Float16* Bh, _Float16* Bl) {
  int tid = threadIdx.x;
  int lane = tid & 63, wid = tid >> 6;
  int wm = wid >> 1, wn = wid & 1;
  int lg = lane >> 4, lc = lane & 15;

  f32x4 acc[2][4] = {};

  size_t sA[2], sB[2];
  int ldst[2];
#pragma unroll
  for (int c = 0; c < 2; ++c) {
    int idxv = c * 512 + tid;
    int m = idxv >> 3;
    int ke = ((idxv & 7) << 3) ^ ((m & 7) << 3);
    sA[c] = (size_t)(m0 + m) * 768 + ke;
    sB[c] = (size_t)(n0 + m) * 768 + ke;
    ldst[c] = (c * 512 + wid * 64) * 8;
  }

  for (int k0 = 0; k0 < 768; k0 += 64) {
    __syncthreads();
#pragma unroll
    for (int c = 0; c < 2; ++c) {
      gload16(Ahi + sA[c] + k0, Ah + ldst[c]);
      gload16(Alo + sA[c] + k0, Al + ldst[c]);
      gload16(Bhi + sB[c] + k0, Bh + ldst[c]);
      gload16(Blo + sB[c] + k0, Bl + ldst[c]);
    }
    __syncthreads();

#pragma unroll
    for (int ks = 0; ks < 2; ++ks) {
      half8 ah[2], al[2], bh[4], bl[4];
#pragma unroll
      for (int mt = 0; mt < 2; ++mt) {
        int ro = kva(wm * 32 + mt * 16 + lc, ks * 64 + (lg << 4));
        ah[mt] = *(half8*)(&Ah[ro]);
        al[mt] = *(half8*)(&Al[ro]);
      }
#pragma unroll
      for (int nf = 0; nf < 4; ++nf) {
        int ro = kva(wn * 64 + nf * 16 + lc, ks * 64 + (lg << 4));
        bh[nf] = *(half8*)(&Bh[ro]);
        bl[nf] = *(half8*)(&Bl[ro]);
      }
#pragma unroll
      for (int mt = 0; mt < 2; ++mt)
#pragma unroll
        for (int nf = 0; nf < 4; ++nf) {
          acc[mt][nf] = mfma_fp16(al[mt], bh[nf], acc[mt][nf]);
          acc[mt][nf] = mfma_fp16(ah[mt], bl[nf], acc[mt][nf]);
          acc[mt][nf] = mfma_fp16(ah[mt], bh[nf], acc[mt][nf]);
        }
    }
  }

#pragma unroll
  for (int mt = 0; mt < 2; ++mt)
#pragma unroll
    for (int nf = 0; nf < 4; ++nf) {
      int col = n0 + wn * 64 + nf * 16 + lc;
      int row0 = m0 + wm * 32 + mt * 16 + (lg << 2);
      float bv = bias[col];
#pragma unroll
      for (int rr = 0; rr < 4; ++rr) {
        int row = row0 + rr;
        float v = acc[mt][nf][rr] + bv;
        _Float16 h = (_Float16)v;
        _Float16 l = (_Float16)(v - (float)h);
        if (mode == 0) {
          Chi[(size_t)row * 768 + col] = h;
          Clo[(size_t)row * 768 + col] = l;
        } else {
          int b = row >> 13, pos = row & 8191;
          int hh = col >> 6, d = col & 63;
          int g = hh >> 2;
          int rdil = 1 << g;
          if ((pos & (rdil - 1)) == g) {
            int t = (pos - g) >> g;
            int Ng = 8192 >> g;
            Chi[vt_base(b, hh) + d * Ng + t] = h;
            Clo[vt_base(b, hh) + d * Ng + t] = l;
          }
        }
      }
    }
}

// fallback: one projection per launch (2D grid, no swizzle)
__global__ __launch_bounds__(512, 2) void gemm3_kernel(
    const _Float16* __restrict__ Ahi, const _Float16* __restrict__ Alo,
    const _Float16* __restrict__ Bhi, const _Float16* __restrict__ Blo,
    const float* __restrict__ bias,
    _Float16* __restrict__ Chi, _Float16* __restrict__ Clo, int mode) {
  __shared__ _Float16 Ah[128 * 64], Al[128 * 64], Bh[128 * 64], Bl[128 * 64];
  gemm3_core(Ahi, Alo, Bhi, Blo, bias, Chi, Clo, mode,
             blockIdx.y * 128, blockIdx.x * 128, Ah, Al, Bh, Bl);
}

// batched: all three projections, 1D grid 2304, XCD-chunked (288/XCD).
__global__ __launch_bounds__(512, 2) void gemm3b_kernel(
    const _Float16* __restrict__ Aqh, const _Float16* __restrict__ Aql,
    const _Float16* __restrict__ Akh, const _Float16* __restrict__ Akl,
    const _Float16* __restrict__ Avh, const _Float16* __restrict__ Avl,
    const _Float16* __restrict__ Wsh, const _Float16* __restrict__ Wsl,
    const float* __restrict__ bq, const float* __restrict__ bk,
    const float* __restrict__ bv,
    _Float16* __restrict__ Qhb, _Float16* __restrict__ Qlb,
    _Float16* __restrict__ Khb, _Float16* __restrict__ Klb,
    _Float16* __restrict__ Vth, _Float16* __restrict__ Vtl) {
  __shared__ _Float16 Ah[128 * 64], Al[128 * 64], Bh[128 * 64], Bl[128 * 64];
  int orig = blockIdx.x;                    // 0..2303, nwg%8==0
  int wg = (orig & 7) * 288 + (orig >> 3);  // bijective XCD chunking
  int sec = wg / 768, rem = wg % 768;
  int m0 = (rem / 6) * 128, n0 = (rem % 6) * 128;
  const _Float16* Ahi = (sec == 0) ? Aqh : (sec == 1) ? Akh : Avh;
  const _Float16* Alo = (sec == 0) ? Aql : (sec == 1) ? Akl : Avl;
  const float* bias = (sec == 0) ? bq : (sec == 1) ? bk : bv;
  _Float16* Chi = (sec == 0) ? Qhb : (sec == 1) ? Khb : Vth;
  _Float16* Clo = (sec == 0) ? Qlb : (sec == 1) ? Klb : Vtl;
  gemm3_core(Ahi, Alo, Wsh + sec * 589824, Wsl + sec * 589824, bias,
             Chi, Clo, (sec == 2) ? 1 : 0, m0, n0, Ah, Al, Bh, Bl);
}

// Output projection: C(fp32) = A(fp16) @ Wt^T + bias. 1D grid 768, XCD-chunked.
__global__ __launch_bounds__(256, 4) void gemm1_kernel(
    const _Float16* __restrict__ A, const _Float16* __restrict__ Bt,
    const float* __restrict__ bias, float* __restrict__ C) {
  __shared__ _Float16 As[128 * 64];
  __shared__ _Float16 Bs[128 * 64];
  int orig = blockIdx.x;                    // 0..767
  int wg = (orig & 7) * 96 + (orig >> 3);   // bijective XCD chunking
  int m0 = (wg / 6) * 128, n0 = (wg % 6) * 128;
  int tid = threadIdx.x;
  int lane = tid & 63, wid = tid >> 6;
  int wm = wid >> 1, wn = wid & 1;
  int lg = lane >> 4, lc = lane & 15;

  f32x4 acc[4][4] = {};

  size_t sA[4], sB[4];
  int ldst[4];
#pragma unroll
  for (int c = 0; c < 4; ++c) {
    int idxv = c * 256 + tid;
    int m = idxv >> 3;
    int ke = ((idxv & 7) << 3) ^ ((m & 7) << 3);
    sA[c] = (size_t)(m0 + m) * 768 + ke;
    sB[c] = (size_t)(n0 + m) * 768 + ke;
    ldst[c] = (c * 256 + wid * 64) * 8;
  }

  for (int k0 = 0; k0 < 768; k0 += 64) {
    __syncthreads();
#pragma unroll
    for (int c = 0; c < 4; ++c) {
      gload16(A + sA[c] + k0, As + ldst[c]);
      gload16(Bt + sB[c] + k0, Bs + ldst[c]);
    }
    __syncthreads();
#pragma unroll
    for (int ks = 0; ks < 2; ++ks) {
      half8 af[4], bf[4];
#pragma unroll
      for (int mt = 0; mt < 4; ++mt)
        af[mt] = *(half8*)(&As[kva(wm * 64 + mt * 16 + lc, ks * 64 + (lg << 4))]);
#pragma unroll
      for (int nf = 0; nf < 4; ++nf)
        bf[nf] = *(half8*)(&Bs[kva(wn * 64 + nf * 16 + lc, ks * 64 + (lg << 4))]);
#pragma unroll
      for (int mt = 0; mt < 4; ++mt)
#pragma unroll
        for (int nf = 0; nf < 4; ++nf)
          acc[mt][nf] = mfma_fp16(af[mt], bf[nf], acc[mt][nf]);
    }
  }

#pragma unroll
  for (int mt = 0; mt < 4; ++mt)
#pragma unroll
    for (int nf = 0; nf < 4; ++nf) {
      int col = n0 + wn * 64 + nf * 16 + lc;
      int row0 = m0 + wm * 64 + mt * 16 + (lg << 2);
      float bv = bias[col];
#pragma unroll
      for (int rr = 0; rr < 4; ++rr)
        C[(size_t)(row0 + rr) * 768 + col] = acc[mt][nf][rr] + bv;
    }
}

// Single-pass dilated flash attention, fp16-pair precision, merged accumulator.
// 4 waves x 32 q rows: each K/V LDS fragment feeds TWO q-tiles. R16 showed the
// structure is right (absmax bit-identical) but (256,3) under-resided (23.6%
// occ). (256,4) = 4 blocks/CU (VGPR cap 128 >= 84 -> same codegen), 896 blocks
// fit one round.
__global__ __launch_bounds__(256, 4) void attn_kernel(
    const _Float16* __restrict__ Qh, const _Float16* __restrict__ Ql,
    const _Float16* __restrict__ Kh, const _Float16* __restrict__ Kl,
    const _Float16* __restrict__ Vth, const _Float16* __restrict__ Vtl,
    _Float16* __restrict__ Xh, float* __restrict__ partial) {
  __shared__ _Float16 Ksh[64 * 64], Ksl[64 * 64];   // XOR-swizzled, stride 64
  __shared__ _Float16 Vsh[64 * 64], Vsl[64 * 64];
  __shared__ float wred[4][64];

  int bid = blockIdx.x;
  int xcd = bid & 7, idx = bid >> 3;
  int u_glob = xcd * 7 + (idx >> 4);
  int qblk = idx & 15;
  int g = (u_glob < 32) ? 0 : (u_glob < 48) ? 1 : 2;
  int u = (g == 0) ? u_glob : (g == 1) ? u_glob - 32 : u_glob - 48;
  int nsegs = 4 >> g;
  int b = u / (nsegs * 4), rem = u % (nsegs * 4);
  int nseg = rem >> 2, hg = rem & 3;
  int head = g * 4 + hg;
  int s = 2048 << g, r = 1 << g, off = g;
  int Ng = 8192 >> g;
  int tbase = nseg * 2048;
  int vbase = vt_base(b, head);

  int tid = threadIdx.x, lane = tid & 63, wid = tid >> 6;  // wid 0..3
  int lg = lane >> 4, lc = lane & 15;

  int q0 = qblk * 128 + wid * 32;
  half8 qAh[2], qAl[2], qBh[2], qBl[2];
  {
    int posA = nseg * s + off + (q0 + lc) * r;
    int posB = nseg * s + off + (q0 + 16 + lc) * r;
    size_t roA = (size_t)(b * 8192 + posA) * 768 + head * 64;
    size_t roB = (size_t)(b * 8192 + posB) * 768 + head * 64;
#pragma unroll
    for (int ks = 0; ks < 2; ++ks) {
      qAh[ks] = *(const half8*)(Qh + roA + ks * 32 + (lg << 3));
      qAl[ks] = *(const half8*)(Ql + roA + ks * 32 + (lg << 3));
      qBh[ks] = *(const half8*)(Qh + roB + ks * 32 + (lg << 3));
      qBl[ks] = *(const half8*)(Ql + roB + ks * 32 + (lg << 3));
    }
  }

  // staging: pass c covers rows c*32 + wid*8 + (lane>>3); 16B per lane.
  int krl = (lane >> 3);                 // 0..7
  int ke = (((lane & 7) ^ krl) << 3);    // pre-swizzled elem col
  size_t kro[2], vro[2];
  int ldk[2];
#pragma unroll
  for (int c = 0; c < 2; ++c) {
    int kr = c * 32 + wid * 8 + krl;
    kro[c] = (size_t)(b * 8192 + nseg * s + off + kr * r) * 768 + head * 64 + ke;
    vro[c] = (size_t)vbase + (size_t)kr * Ng + tbase + ke;
    ldk[c] = c * 2048 + wid * 512;       // wave-uniform element base
  }
  const size_t kstep = (size_t)64 * r * 768;

  f32x4 accA[4] = {};
  f32x4 accB[4] = {};
  float lsumA = 0.f, lsumB = 0.f;

  const int sl0 = ((lane & 16) << 1) + lc;
  const int sl1 = sl0 + 16;
  const bool hiSel = (lane & 32) != 0;

  for (int kt = 0; kt < 32; ++kt) {
    __syncthreads();                 // readers done with previous tile
#pragma unroll
    for (int c = 0; c < 2; ++c) {
      gload16(Kh + kro[c], Ksh + ldk[c]);
      gload16(Kl + kro[c], Ksl + ldk[c]);
      gload16(Vth + vro[c], Vsh + ldk[c]);
      gload16(Vtl + vro[c], Vsl + ldk[c]);
      kro[c] += kstep;
      vro[c] += 64;
    }
    __syncthreads();                 // vmcnt drained -> tile ready

    // S^T = K·Q for both q-tiles; exp+pack fused per nf
    unsigned int pkA[4][2], pkB[4][2];
#pragma unroll
    for (int nf = 0; nf < 4; ++nf) {
      half8 kh[2], kl[2];
#pragma unroll
      for (int ks = 0; ks < 2; ++ks) {
        int ro = kva(nf * 16 + lc, ks * 64 + (lg << 4));
        kh[ks] = *(half8*)(&Ksh[ro]);
        kl[ks] = *(half8*)(&Ksl[ro]);
      }
      f32x4 tA = {}, tB = {};
#pragma unroll
      for (int ks = 0; ks < 2; ++ks) {
        tA = mfma_fp16(kl[ks], qAh[ks], tA);
        tA = mfma_fp16(kh[ks], qAl[ks], tA);
        tB = mfma_fp16(kl[ks], qBh[ks], tB);
        tB = mfma_fp16(kh[ks], qBl[ks], tB);
      }
#pragma unroll
      for (int ks = 0; ks < 2; ++ks) {
        tA = mfma_fp16(kh[ks], qAh[ks], tA);
        tB = mfma_fp16(kh[ks], qBh[ks], tB);
      }
      _Float16 hA[4], hB[4];
#pragma unroll
      for (int rr = 0; rr < 4; ++rr) {
        float pA = __expf(tA[rr] * 0.125f);
        float pB = __expf(tB[rr] * 0.125f);
        hA[rr] = (_Float16)pA; lsumA += (float)hA[rr];
        hB[rr] = (_Float16)pB; lsumB += (float)hB[rr];
      }
      half2v a01 = {hA[0], hA[1]}, a23 = {hA[2], hA[3]};
      half2v b01 = {hB[0], hB[1]}, b23 = {hB[2], hB[3]};
      pkA[nf][0] = __builtin_bit_cast(unsigned int, a01);
      pkA[nf][1] = __builtin_bit_cast(unsigned int, a23);
      pkB[nf][0] = __builtin_bit_cast(unsigned int, b01);
      pkB[nf][1] = __builtin_bit_cast(unsigned int, b23);
    }

    // PV: V fragments read ONCE, feed both tiles
#pragma unroll
    for (int ks2 = 0; ks2 < 2; ++ks2) {
      int nfA = 2 * ks2, nfB = 2 * ks2 + 1;
      unsigned int aA0 = __shfl(pkA[nfA][0], sl0, 64);
      unsigned int aB0 = __shfl(pkA[nfB][0], sl0, 64);
      unsigned int aA1 = __shfl(pkA[nfA][1], sl0, 64);
      unsigned int aB1 = __shfl(pkA[nfB][1], sl0, 64);
      unsigned int aA2 = __shfl(pkA[nfA][0], sl1, 64);
      unsigned int aB2 = __shfl(pkA[nfB][0], sl1, 64);
      unsigned int aA3 = __shfl(pkA[nfA][1], sl1, 64);
      unsigned int aB3 = __shfl(pkA[nfB][1], sl1, 64);
      u32x4 pwA;
      pwA[0] = hiSel ? aB0 : aA0;
      pwA[1] = hiSel ? aB1 : aA1;
      pwA[2] = hiSel ? aB2 : aA2;
      pwA[3] = hiSel ? aB3 : aA3;
      half8 paA = __builtin_bit_cast(half8, pwA);

      unsigned int bA0 = __shfl(pkB[nfA][0], sl0, 64);
      unsigned int bB0 = __shfl(pkB[nfB][0], sl0, 64);
      unsigned int bA1 = __shfl(pkB[nfA][1], sl0, 64);
      unsigned int bB1 = __shfl(pkB[nfB][1], sl0, 64);
      unsigned int bA2 = __shfl(pkB[nfA][0], sl1, 64);
      unsigned int bB2 = __shfl(pkB[nfB][0], sl1, 64);
      unsigned int bA3 = __shfl(pkB[nfA][1], sl1, 64);
      unsigned int bB3 = __shfl(pkB[nfB][1], sl1, 64);
      u32x4 pwB;
      pwB[0] = hiSel ? bB0 : bA0;
      pwB[1] = hiSel ? bB1 : bA1;
      pwB[2] = hiSel ? bB2 : bA2;
      pwB[3] = hiSel ? bB3 : bA3;
      half8 paB = __builtin_bit_cast(half8, pwB);

#pragma unroll
      for (int nf = 0; nf < 4; ++nf) {
        int ro = kva(nf * 16 + lc, ks2 * 64 + (lg << 4));
        half8 vh = *(half8*)(&Vsh[ro]);
        half8 vl = *(half8*)(&Vsl[ro]);
        accA[nf] = mfma_fp16(paA, vl, accA[nf]);
        accA[nf] = mfma_fp16(paA, vh, accA[nf]);
        accB[nf] = mfma_fp16(paB, vl, accB[nf]);
        accB[nf] = mfma_fp16(paB, vh, accB[nf]);
      }
    }
  }

  // row sums: combine the 4 lg groups per tile
  lsumA += __shfl_xor(lsumA, 16, 64);
  lsumA += __shfl_xor(lsumA, 32, 64);
  lsumB += __shfl_xor(lsumB, 16, 64);
  lsumB += __shfl_xor(lsumB, 32, 64);
  float invA = 1.0f / lsumA;
  float invB = 1.0f / lsumB;

  // epilogue: store fp16 X for both tiles; column sums from ROUNDED values
  float cs[4] = {};
#pragma unroll
  for (int rr = 0; rr < 4; ++rr) {
    int qi = ((lane >> 4) & 3) * 4 + rr;
    float invqA = __shfl(invA, (lane & 48) + qi, 64);
    float invqB = __shfl(invB, (lane & 48) + qi, 64);
    int posA = nseg * s + off + (q0 + qi) * r;
    int posB = nseg * s + off + (q0 + 16 + qi) * r;
    _Float16* xrA = Xh + (size_t)(b * 8192 + posA) * 768 + head * 64;
    _Float16* xrB = Xh + (size_t)(b * 8192 + posB) * 768 + head * 64;
#pragma unroll
    for (int nf = 0; nf < 4; ++nf) {
      _Float16 hxA = (_Float16)(accA[nf][rr] * invqA);
      _Float16 hxB = (_Float16)(accB[nf][rr] * invqB);
      xrA[nf * 16 + lc] = hxA;
      xrB[nf * 16 + lc] = hxB;
      cs[nf] += (float)hxA + (float)hxB;
    }
  }
#pragma unroll
  for (int nf = 0; nf < 4; ++nf) {
    cs[nf] += __shfl_xor(cs[nf], 16, 64);
    cs[nf] += __shfl_xor(cs[nf], 32, 64);
    if (lane < 16) wred[wid][nf * 16 + lc] = cs[nf];
  }
  __syncthreads();
  if (tid < 64) {
    float w4 = wred[0][tid] + wred[1][tid] + wred[2][tid] + wred[3][tid];
    int slot = ((b * 12 + head) * 64 + nseg * 16 + qblk);
    partial[slot * 64 + tid] = w4;
  }
}

// div[b*768 + h*64 + d] = sum over this head's (nsegs*16) block partials
__global__ __launch_bounds__(256) void colsum2_kernel(const float* __restrict__ partial,
                                                      float* __restrict__ divbuf) {
  int i = blockIdx.x * 256 + threadIdx.x;  // 0..1535
  int b = i / 768, e = i % 768;
  int h = e >> 6, d = e & 63;
  int g = h >> 2;
  int nslots = 64 >> g;
  const float* src = partial + (size_t)((b * 12 + h) * 64) * 64 + d;
  float sacc = 0.f;
  for (int c = 0; c < nslots; ++c) sacc += src[c * 64];
  divbuf[i] = sacc;
}

// LayerNorm, wave-per-row: fp16 in/out, fuses /(div*3) + written-slot mask.
__global__ __launch_bounds__(256) void ln_kernel(const _Float16* __restrict__ Xh,
                                                 _Float16* __restrict__ Xln,
                                                 const float* __restrict__ divbuf,
                                                 const float* __restrict__ ln_w,
                                                 const float* __restrict__ ln_b) {
  int wid = threadIdx.x >> 6, lane = threadIdx.x & 63;
  int row = blockIdx.x * 4 + wid;
  int b = row >> 13, pos = row & 8191;
  float x[12];
  float s1 = 0.f, s2 = 0.f;
#pragma unroll
  for (int j = 0; j < 12; ++j) {
    int e = lane + 64 * j;
    int g = j >> 2;
    bool wr = (g == 0) || (g == 1 && (pos & 1) == 1) || (g == 2 && (pos & 3) == 2);
    float v = 0.f;
    if (wr) v = (float)Xh[(size_t)row * 768 + e] / (divbuf[b * 768 + e] * 3.0f);
    x[j] = v;
    s1 += v;
    s2 += v * v;
  }
#pragma unroll
  for (int msk = 1; msk < 64; msk <<= 1) {
    s1 += __shfl_xor(s1, msk, 64);
    s2 += __shfl_xor(s2, msk, 64);
  }
  float mean = s1 * (1.0f / 768.0f);
  float var = s2 * (1.0f / 768.0f) - mean * mean;
  float inv = rsqrtf(var + 1e-5f);
#pragma unroll
  for (int j = 0; j < 12; ++j) {
    int e = lane + 64 * j;
    Xln[(size_t)row * 768 + e] = (_Float16)((x[j] - mean) * inv * ln_w[e] + ln_b[e]);
  }
}

extern "C" void kernel_launch(void* const* d_in, const int* in_sizes, int n_in,
                              void* d_out, int out_size, void* d_ws, size_t ws_size,
                              hipStream_t stream) {
  const float* query = (const float*)d_in[0];
  const float* key   = (const float*)d_in[1];
  const float* value = (const float*)d_in[2];
  const float* Wq = (const float*)d_in[3];
  const float* bq = (const float*)d_in[4];
  const float* Wk = (const float*)d_in[5];
  const float* bk = (const float*)d_in[6];
  const float* Wv = (const float*)d_in[7];
  const float* bv = (const float*)d_in[8];
  const float* Wo = (const float*)d_in[9];
  const float* bo = (const float*)d_in[10];
  const float* ln_w = (const float*)d_in[11];
  const float* ln_b = (const float*)d_in[12];

  char* ws = (char*)d_ws;
  _Float16* Wsh = (_Float16*)ws; ws += (size_t)4 * 589824 * 2;
  _Float16* Wsl = (_Float16*)ws; ws += (size_t)4 * 589824 * 2;
  _Float16* Qhb = (_Float16*)ws; ws += (size_t)16384 * 768 * 2;
  _Float16* Qlb = (_Float16*)ws; ws += (size_t)16384 * 768 * 2;
  _Float16* Khb = (_Float16*)ws; ws += (size_t)16384 * 768 * 2;
  _Float16* Klb = (_Float16*)ws; ws += (size_t)16384 * 768 * 2;
  _Float16* Vth = (_Float16*)ws; ws += (size_t)7340032 * 2;
  _Float16* Vtl = (_Float16*)ws; ws += (size_t)7340032 * 2;
  char* Xregion = ws; ws += (size_t)16384 * 768 * 4;   // Xh + Xln (fp16 each)
  float* partial = (float*)ws; ws += (size_t)24 * 64 * 64 * 4;
  float* divbuf = (float*)ws; ws += 2 * 768 * 4;

  _Float16* Xh  = (_Float16*)Xregion;
  _Float16* Xln = Xh + (size_t)16384 * 768;
  _Float16* Aqh = (_Float16*)Xregion;
  _Float16* Aql = Aqh + (size_t)16384 * 768;

  size_t base_bytes = (size_t)(ws - (char*)d_ws);
  size_t extra = (size_t)4 * 16384 * 768 * 2;
  bool batched = ws_size >= base_bytes + extra;

  wsplit4_kernel<<<dim3(2304, 4), 256, 0, stream>>>(Wq, Wk, Wv, Wo, Wsh, Wsl);

  dim3 ggrid(6, 128);
  if (batched) {
    _Float16* Akh = (_Float16*)ws; ws += (size_t)16384 * 768 * 2;
    _Float16* Akl = (_Float16*)ws; ws += (size_t)16384 * 768 * 2;
    _Float16* Avh = (_Float16*)ws; ws += (size_t)16384 * 768 * 2;
    _Float16* Avl = (_Float16*)ws; ws += (size_t)16384 * 768 * 2;
    asplit3_kernel<<<dim3(6144, 3), 256, 0, stream>>>(query, key, value,
        Aqh, Aql, Akh, Akl, Avh, Avl);
    gemm3b_kernel<<<2304, 512, 0, stream>>>(
        Aqh, Aql, Akh, Akl, Avh, Avl, Wsh, Wsl, bq, bk, bv,
        Qhb, Qlb, Khb, Klb, Vth, Vtl);
  } else {
    asplit_kernel<<<6144, 256, 0, stream>>>(query, Aqh, Aql);
    gemm3_kernel<<<ggrid, 512, 0, stream>>>(Aqh, Aql, Wsh, Wsl, bq, Qhb, Qlb, 0);
    asplit_kernel<<<6144, 256, 0, stream>>>(key, Aqh, Aql);
    gemm3_kernel<<<ggrid, 512, 0, stream>>>(Aqh, Aql, Wsh + 589824, Wsl + 589824, bk, Khb, Klb, 0);
    asplit_kernel<<<6144, 256, 0, stream>>>(value, Aqh, Aql);
    gemm3_kernel<<<ggrid, 512, 0, stream>>>(Aqh, Aql, Wsh + 2 * 589824, Wsl + 2 * 589824, bv, Vth, Vtl, 1);
  }

  attn_kernel<<<896, 256, 0, stream>>>(Qhb, Qlb, Khb, Klb, Vth, Vtl, Xh, partial);

  colsum2_kernel<<<6, 256, 0, stream>>>(partial, divbuf);
  ln_kernel<<<4096, 256, 0, stream>>>(Xh, Xln, divbuf, ln_w, ln_b);

  gemm1_kernel<<<768, 256, 0, stream>>>(Xln, Wsh + 3 * 589824, bo, (float*)d_out);
}

// Round 18
// 537.551 us; speedup vs baseline: 1.1704x; 1.1493x over previous
//
#include <hip/hip_runtime.h>

typedef __attribute__((ext_vector_type(4))) float f32x4;
typedef __attribute__((ext_vector_type(4))) unsigned int u32x4;
typedef __attribute__((ext_vector_type(8))) _Float16 half8;
typedef __attribute__((ext_vector_type(2))) _Float16 half2v;

__device__ inline f32x4 mfma_fp16(half8 a, half8 b, f32x4 c) {
  return __builtin_amdgcn_mfma_f32_16x16x32_f16(a, b, c, 0, 0, 0);
}

// XOR-swizzled element index, [rows][64 cols] fp16 tile (row stride 128B).
__device__ inline int kva(int row, int colbyte) {
  return ((row * 128 + colbyte) ^ ((row & 7) << 4)) >> 1;
}

// async global->LDS, 16B/lane; LDS dest = wave-uniform base + lane*16 (linear).
__device__ inline void gload16(const _Float16* g, _Float16* l) {
  __builtin_amdgcn_global_load_lds(
      (const __attribute__((address_space(1))) void*)g,
      (__attribute__((address_space(3))) void*)l, 16, 0, 0);
}

// All 4 weight matrices (K x N fp32) -> transposed fp16 hi/lo planes (N x K).
// lo = UNSCALED residual.
__global__ __launch_bounds__(256) void wsplit4_kernel(
    const float* __restrict__ Wq, const float* __restrict__ Wk,
    const float* __restrict__ Wv, const float* __restrict__ Wo,
    _Float16* __restrict__ Whi, _Float16* __restrict__ Wlo) {
  int w = blockIdx.y;
  const float* W = (w == 0) ? Wq : (w == 1) ? Wk : (w == 2) ? Wv : Wo;
  int i = blockIdx.x * 256 + threadIdx.x;
  int k = i / 768, n = i % 768;
  float v = W[i];
  _Float16 h = (_Float16)v;
  Whi[w * 589824 + n * 768 + k] = h;
  Wlo[w * 589824 + n * 768 + k] = (_Float16)(v - (float)h);
}

// Vt plane base (in elements) for (b, head). Per-b size = 3,670,016 elems.
__device__ inline int vt_base(int b, int h) {
  int base = b * 3670016;
  if (h < 4)      base += h * 524288;
  else if (h < 8) base += 2097152 + (h - 4) * 262144;
  else            base += 3145728 + (h - 8) * 131072;
  return base;
}

// High-precision projection GEMM, fp16-pair split, merged fp32 accumulator.
// A read as RAW fp32, split in registers, ds_write'd into kva layout (fuses
// the former asplit pass; same bytes staged, same split math, same MFMA order
// -> bit-identical numerics). B/W planes staged via global_load_lds with
// pre-swizzled source (G21). BK=64, (512,2) — the proven R13 structure.
__device__ __forceinline__ void gemm3_core(
    const float* __restrict__ Araw,
    const _Float16* __restrict__ Bhi, const _Float16* __restrict__ Blo,
    const float* __restrict__ bias, _Float16* __restrict__ Chi,
    _Float16* __restrict__ Clo, int mode, int m0, int n0,
    _Float16* Ah, _Float16* Al, _Float16* Bh, _Float16* Bl) {
  int tid = threadIdx.x;
  int lane = tid & 63, wid = tid >> 6;
  int wm = wid >> 1, wn = wid & 1;
  int lg = lane >> 4, lc = lane & 15;

  f32x4 acc[2][4] = {};

  size_t aoff[2], sB[2];
  int lA[2], ldst[2];
#pragma unroll
  for (int c = 0; c < 2; ++c) {
    int idxv = c * 512 + tid;
    int mrow = idxv >> 3, ch = idxv & 7;
    aoff[c] = (size_t)(m0 + mrow) * 768 + ch * 8;           // linear fp32 source
    lA[c] = kva(mrow, ch << 4);                              // swizzled LDS dest
    int ke = (ch << 3) ^ ((mrow & 7) << 3);                  // pre-swizzled col
    sB[c] = (size_t)(n0 + mrow) * 768 + ke;
    ldst[c] = (c * 512 + wid * 64) * 8;                      // linear LDS dest
  }

  for (int k0 = 0; k0 < 768; k0 += 64) {
    __syncthreads();
#pragma unroll
    for (int c = 0; c < 2; ++c) {
      // A: fp32 -> hi/lo halves -> swizzled ds_write
      f32x4 x0 = *(const f32x4*)(Araw + aoff[c] + k0);
      f32x4 x1 = *(const f32x4*)(Araw + aoff[c] + k0 + 4);
      half8 vh, vl;
#pragma unroll
      for (int j = 0; j < 4; ++j) {
        _Float16 h0 = (_Float16)x0[j];
        vh[j] = h0; vl[j] = (_Float16)(x0[j] - (float)h0);
        _Float16 h1 = (_Float16)x1[j];
        vh[4 + j] = h1; vl[4 + j] = (_Float16)(x1[j] - (float)h1);
      }
      *(half8*)(&Ah[lA[c]]) = vh;
      *(half8*)(&Al[lA[c]]) = vl;
      // B: async direct-to-LDS
      gload16(Bhi + sB[c] + k0, Bh + ldst[c]);
      gload16(Blo + sB[c] + k0, Bl + ldst[c]);
    }
    __syncthreads();   // lgkm + vmcnt drained -> tile ready

#pragma unroll
    for (int ks = 0; ks < 2; ++ks) {
      half8 ah[2], al[2], bh[4], bl[4];
#pragma unroll
      for (int mt = 0; mt < 2; ++mt) {
        int ro = kva(wm * 32 + mt * 16 + lc, ks * 64 + (lg << 4));
        ah[mt] = *(half8*)(&Ah[ro]);
        al[mt] = *(half8*)(&Al[ro]);
      }
#pragma unroll
      for (int nf = 0; nf < 4; ++nf) {
        int ro = kva(wn * 64 + nf * 16 + lc, ks * 64 + (lg << 4));
        bh[nf] = *(half8*)(&Bh[ro]);
        bl[nf] = *(half8*)(&Bl[ro]);
      }
#pragma unroll
      for (int mt = 0; mt < 2; ++mt)
#pragma unroll
        for (int nf = 0; nf < 4; ++nf) {
          acc[mt][nf] = mfma_fp16(al[mt], bh[nf], acc[mt][nf]);
          acc[mt][nf] = mfma_fp16(ah[mt], bl[nf], acc[mt][nf]);
          acc[mt][nf] = mfma_fp16(ah[mt], bh[nf], acc[mt][nf]);
        }
    }
  }

#pragma unroll
  for (int mt = 0; mt < 2; ++mt)
#pragma unroll
    for (int nf = 0; nf < 4; ++nf) {
      int col = n0 + wn * 64 + nf * 16 + lc;
      int row0 = m0 + wm * 32 + mt * 16 + (lg << 2);
      float bv = bias[col];
#pragma unroll
      for (int rr = 0; rr < 4; ++rr) {
        int row = row0 + rr;
        float v = acc[mt][nf][rr] + bv;
        _Float16 h = (_Float16)v;
        _Float16 l = (_Float16)(v - (float)h);
        if (mode == 0) {
          Chi[(size_t)row * 768 + col] = h;
          Clo[(size_t)row * 768 + col] = l;
        } else {
          int b = row >> 13, pos = row & 8191;
          int hh = col >> 6, d = col & 63;
          int g = hh >> 2;
          int rdil = 1 << g;
          if ((pos & (rdil - 1)) == g) {
            int t = (pos - g) >> g;
            int Ng = 8192 >> g;
            Chi[vt_base(b, hh) + d * Ng + t] = h;
            Clo[vt_base(b, hh) + d * Ng + t] = l;
          }
        }
      }
    }
}

// all three projections, 1D grid 2304, XCD-chunked (288/XCD), raw fp32 A.
__global__ __launch_bounds__(512, 2) void gemm3b_kernel(
    const float* __restrict__ query, const float* __restrict__ key,
    const float* __restrict__ value,
    const _Float16* __restrict__ Wsh, const _Float16* __restrict__ Wsl,
    const float* __restrict__ bq, const float* __restrict__ bk,
    const float* __restrict__ bv,
    _Float16* __restrict__ Qhb, _Float16* __restrict__ Qlb,
    _Float16* __restrict__ Khb, _Float16* __restrict__ Klb,
    _Float16* __restrict__ Vth, _Float16* __restrict__ Vtl) {
  __shared__ _Float16 Ah[128 * 64], Al[128 * 64], Bh[128 * 64], Bl[128 * 64];
  int orig = blockIdx.x;                    // 0..2303, nwg%8==0
  int wg = (orig & 7) * 288 + (orig >> 3);  // bijective XCD chunking
  int sec = wg / 768, rem = wg % 768;
  int m0 = (rem / 6) * 128, n0 = (rem % 6) * 128;
  const float* Araw = (sec == 0) ? query : (sec == 1) ? key : value;
  const float* bias = (sec == 0) ? bq : (sec == 1) ? bk : bv;
  _Float16* Chi = (sec == 0) ? Qhb : (sec == 1) ? Khb : Vth;
  _Float16* Clo = (sec == 0) ? Qlb : (sec == 1) ? Klb : Vtl;
  gemm3_core(Araw, Wsh + sec * 589824, Wsl + sec * 589824, bias,
             Chi, Clo, (sec == 2) ? 1 : 0, m0, n0, Ah, Al, Bh, Bl);
}

// Output projection: C(fp32) = A(fp16) @ Wt^T + bias. 1D grid 768, XCD-chunked.
__global__ __launch_bounds__(256, 4) void gemm1_kernel(
    const _Float16* __restrict__ A, const _Float16* __restrict__ Bt,
    const float* __restrict__ bias, float* __restrict__ C) {
  __shared__ _Float16 As[128 * 64];
  __shared__ _Float16 Bs[128 * 64];
  int orig = blockIdx.x;                    // 0..767
  int wg = (orig & 7) * 96 + (orig >> 3);   // bijective XCD chunking
  int m0 = (wg / 6) * 128, n0 = (wg % 6) * 128;
  int tid = threadIdx.x;
  int lane = tid & 63, wid = tid >> 6;
  int wm = wid >> 1, wn = wid & 1;
  int lg = lane >> 4, lc = lane & 15;

  f32x4 acc[4][4] = {};

  size_t sA[4], sB[4];
  int ldst[4];
#pragma unroll
  for (int c = 0; c < 4; ++c) {
    int idxv = c * 256 + tid;
    int m = idxv >> 3;
    int ke = ((idxv & 7) << 3) ^ ((m & 7) << 3);
    sA[c] = (size_t)(m0 + m) * 768 + ke;
    sB[c] = (size_t)(n0 + m) * 768 + ke;
    ldst[c] = (c * 256 + wid * 64) * 8;
  }

  for (int k0 = 0; k0 < 768; k0 += 64) {
    __syncthreads();
#pragma unroll
    for (int c = 0; c < 4; ++c) {
      gload16(A + sA[c] + k0, As + ldst[c]);
      gload16(Bt + sB[c] + k0, Bs + ldst[c]);
    }
    __syncthreads();
#pragma unroll
    for (int ks = 0; ks < 2; ++ks) {
      half8 af[4], bf[4];
#pragma unroll
      for (int mt = 0; mt < 4; ++mt)
        af[mt] = *(half8*)(&As[kva(wm * 64 + mt * 16 + lc, ks * 64 + (lg << 4))]);
#pragma unroll
      for (int nf = 0; nf < 4; ++nf)
        bf[nf] = *(half8*)(&Bs[kva(wn * 64 + nf * 16 + lc, ks * 64 + (lg << 4))]);
#pragma unroll
      for (int mt = 0; mt < 4; ++mt)
#pragma unroll
        for (int nf = 0; nf < 4; ++nf)
          acc[mt][nf] = mfma_fp16(af[mt], bf[nf], acc[mt][nf]);
    }
  }

#pragma unroll
  for (int mt = 0; mt < 4; ++mt)
#pragma unroll
    for (int nf = 0; nf < 4; ++nf) {
      int col = n0 + wn * 64 + nf * 16 + lc;
      int row0 = m0 + wm * 64 + mt * 16 + (lg << 2);
      float bv = bias[col];
#pragma unroll
      for (int rr = 0; rr < 4; ++rr)
        C[(size_t)(row0 + rr) * 768 + col] = acc[mt][nf][rr] + bv;
    }
}

// Single-pass dilated flash attention (R17 form — practical floor ~204us;
// two structural rewrites landed neutral, pipes balanced at ~35% each).
__global__ __launch_bounds__(256, 4) void attn_kernel(
    const _Float16* __restrict__ Qh, const _Float16* __restrict__ Ql,
    const _Float16* __restrict__ Kh, const _Float16* __restrict__ Kl,
    const _Float16* __restrict__ Vth, const _Float16* __restrict__ Vtl,
    _Float16* __restrict__ Xh, float* __restrict__ partial) {
  __shared__ _Float16 Ksh[64 * 64], Ksl[64 * 64];   // XOR-swizzled, stride 64
  __shared__ _Float16 Vsh[64 * 64], Vsl[64 * 64];
  __shared__ float wred[4][64];

  int bid = blockIdx.x;
  int xcd = bid & 7, idx = bid >> 3;
  int u_glob = xcd * 7 + (idx >> 4);
  int qblk = idx & 15;
  int g = (u_glob < 32) ? 0 : (u_glob < 48) ? 1 : 2;
  int u = (g == 0) ? u_glob : (g == 1) ? u_glob - 32 : u_glob - 48;
  int nsegs = 4 >> g;
  int b = u / (nsegs * 4), rem = u % (nsegs * 4);
  int nseg = rem >> 2, hg = rem & 3;
  int head = g * 4 + hg;
  int s = 2048 << g, r = 1 << g, off = g;
  int Ng = 8192 >> g;
  int tbase = nseg * 2048;
  int vbase = vt_base(b, head);

  int tid = threadIdx.x, lane = tid & 63, wid = tid >> 6;  // wid 0..3
  int lg = lane >> 4, lc = lane & 15;

  int q0 = qblk * 128 + wid * 32;
  half8 qAh[2], qAl[2], qBh[2], qBl[2];
  {
    int posA = nseg * s + off + (q0 + lc) * r;
    int posB = nseg * s + off + (q0 + 16 + lc) * r;
    size_t roA = (size_t)(b * 8192 + posA) * 768 + head * 64;
    size_t roB = (size_t)(b * 8192 + posB) * 768 + head * 64;
#pragma unroll
    for (int ks = 0; ks < 2; ++ks) {
      qAh[ks] = *(const half8*)(Qh + roA + ks * 32 + (lg << 3));
      qAl[ks] = *(const half8*)(Ql + roA + ks * 32 + (lg << 3));
      qBh[ks] = *(const half8*)(Qh + roB + ks * 32 + (lg << 3));
      qBl[ks] = *(const half8*)(Ql + roB + ks * 32 + (lg << 3));
    }
  }

  int krl = (lane >> 3);                 // 0..7
  int ke = (((lane & 7) ^ krl) << 3);    // pre-swizzled elem col
  size_t kro[2], vro[2];
  int ldk[2];
#pragma unroll
  for (int c = 0; c < 2; ++c) {
    int kr = c * 32 + wid * 8 + krl;
    kro[c] = (size_t)(b * 8192 + nseg * s + off + kr * r) * 768 + head * 64 + ke;
    vro[c] = (size_t)vbase + (size_t)kr * Ng + tbase + ke;
    ldk[c] = c * 2048 + wid * 512;       // wave-uniform element base
  }
  const size_t kstep = (size_t)64 * r * 768;

  f32x4 accA[4] = {};
  f32x4 accB[4] = {};
  float lsumA = 0.f, lsumB = 0.f;

  const int sl0 = ((lane & 16) << 1) + lc;
  const int sl1 = sl0 + 16;
  const bool hiSel = (lane & 32) != 0;

  for (int kt = 0; kt < 32; ++kt) {
    __syncthreads();                 // readers done with previous tile
#pragma unroll
    for (int c = 0; c < 2; ++c) {
      gload16(Kh + kro[c], Ksh + ldk[c]);
      gload16(Kl + kro[c], Ksl + ldk[c]);
      gload16(Vth + vro[c], Vsh + ldk[c]);
      gload16(Vtl + vro[c], Vsl + ldk[c]);
      kro[c] += kstep;
      vro[c] += 64;
    }
    __syncthreads();                 // vmcnt drained -> tile ready

    unsigned int pkA[4][2], pkB[4][2];
#pragma unroll
    for (int nf = 0; nf < 4; ++nf) {
      half8 kh[2], kl[2];
#pragma unroll
      for (int ks = 0; ks < 2; ++ks) {
        int ro = kva(nf * 16 + lc, ks * 64 + (lg << 4));
        kh[ks] = *(half8*)(&Ksh[ro]);
        kl[ks] = *(half8*)(&Ksl[ro]);
      }
      f32x4 tA = {}, tB = {};
#pragma unroll
      for (int ks = 0; ks < 2; ++ks) {
        tA = mfma_fp16(kl[ks], qAh[ks], tA);
        tA = mfma_fp16(kh[ks], qAl[ks], tA);
        tB = mfma_fp16(kl[ks], qBh[ks], tB);
        tB = mfma_fp16(kh[ks], qBl[ks], tB);
      }
#pragma unroll
      for (int ks = 0; ks < 2; ++ks) {
        tA = mfma_fp16(kh[ks], qAh[ks], tA);
        tB = mfma_fp16(kh[ks], qBh[ks], tB);
      }
      _Float16 hA[4], hB[4];
#pragma unroll
      for (int rr = 0; rr < 4; ++rr) {
        float pA = __expf(tA[rr] * 0.125f);
        float pB = __expf(tB[rr] * 0.125f);
        hA[rr] = (_Float16)pA; lsumA += (float)hA[rr];
        hB[rr] = (_Float16)pB; lsumB += (float)hB[rr];
      }
      half2v a01 = {hA[0], hA[1]}, a23 = {hA[2], hA[3]};
      half2v b01 = {hB[0], hB[1]}, b23 = {hB[2], hB[3]};
      pkA[nf][0] = __builtin_bit_cast(unsigned int, a01);
      pkA[nf][1] = __builtin_bit_cast(unsigned int, a23);
      pkB[nf][0] = __builtin_bit_cast(unsigned int, b01);
      pkB[nf][1] = __builtin_bit_cast(unsigned int, b23);
    }

#pragma unroll
    for (int ks2 = 0; ks2 < 2; ++ks2) {
      int nfA = 2 * ks2, nfB = 2 * ks2 + 1;
      unsigned int aA0 = __shfl(pkA[nfA][0], sl0, 64);
      unsigned int aB0 = __shfl(pkA[nfB][0], sl0, 64);
      unsigned int aA1 = __shfl(pkA[nfA][1], sl0, 64);
      unsigned int aB1 = __shfl(pkA[nfB][1], sl0, 64);
      unsigned int aA2 = __shfl(pkA[nfA][0], sl1, 64);
      unsigned int aB2 = __shfl(pkA[nfB][0], sl1, 64);
      unsigned int aA3 = __shfl(pkA[nfA][1], sl1, 64);
      unsigned int aB3 = __shfl(pkA[nfB][1], sl1, 64);
      u32x4 pwA;
      pwA[0] = hiSel ? aB0 : aA0;
      pwA[1] = hiSel ? aB1 : aA1;
      pwA[2] = hiSel ? aB2 : aA2;
      pwA[3] = hiSel ? aB3 : aA3;
      half8 paA = __builtin_bit_cast(half8, pwA);

      unsigned int bA0 = __shfl(pkB[nfA][0], sl0, 64);
      unsigned int bB0 = __shfl(pkB[nfB][0], sl0, 64);
      unsigned int bA1 = __shfl(pkB[nfA][1], sl0, 64);
      unsigned int bB1 = __shfl(pkB[nfB][1], sl0, 64);
      unsigned int bA2 = __shfl(pkB[nfA][0], sl1, 64);
      unsigned int bB2 = __shfl(pkB[nfB][0], sl1, 64);
      unsigned int bA3 = __shfl(pkB[nfA][1], sl1, 64);
      unsigned int bB3 = __shfl(pkB[nfB][1], sl1, 64);
      u32x4 pwB;
      pwB[0] = hiSel ? bB0 : bA0;
      pwB[1] = hiSel ? bB1 : bA1;
      pwB[2] = hiSel ? bB2 : bA2;
      pwB[3] = hiSel ? bB3 : bA3;
      half8 paB = __builtin_bit_cast(half8, pwB);

#pragma unroll
      for (int nf = 0; nf < 4; ++nf) {
        int ro = kva(nf * 16 + lc, ks2 * 64 + (lg << 4));
        half8 vh = *(half8*)(&Vsh[ro]);
        half8 vl = *(half8*)(&Vsl[ro]);
        accA[nf] = mfma_fp16(paA, vl, accA[nf]);
        accA[nf] = mfma_fp16(paA, vh, accA[nf]);
        accB[nf] = mfma_fp16(paB, vl, accB[nf]);
        accB[nf] = mfma_fp16(paB, vh, accB[nf]);
      }
    }
  }

  lsumA += __shfl_xor(lsumA, 16, 64);
  lsumA += __shfl_xor(lsumA, 32, 64);
  lsumB += __shfl_xor(lsumB, 16, 64);
  lsumB += __shfl_xor(lsumB, 32, 64);
  float invA = 1.0f / lsumA;
  float invB = 1.0f / lsumB;

  float cs[4] = {};
#pragma unroll
  for (int rr = 0; rr < 4; ++rr) {
    int qi = ((lane >> 4) & 3) * 4 + rr;
    float invqA = __shfl(invA, (lane & 48) + qi, 64);
    float invqB = __shfl(invB, (lane & 48) + qi, 64);
    int posA = nseg * s + off + (q0 + qi) * r;
    int posB = nseg * s + off + (q0 + 16 + qi) * r;
    _Float16* xrA = Xh + (size_t)(b * 8192 + posA) * 768 + head * 64;
    _Float16* xrB = Xh + (size_t)(b * 8192 + posB) * 768 + head * 64;
#pragma unroll
    for (int nf = 0; nf < 4; ++nf) {
      _Float16 hxA = (_Float16)(accA[nf][rr] * invqA);
      _Float16 hxB = (_Float16)(accB[nf][rr] * invqB);
      xrA[nf * 16 + lc] = hxA;
      xrB[nf * 16 + lc] = hxB;
      cs[nf] += (float)hxA + (float)hxB;
    }
  }
#pragma unroll
  for (int nf = 0; nf < 4; ++nf) {
    cs[nf] += __shfl_xor(cs[nf], 16, 64);
    cs[nf] += __shfl_xor(cs[nf], 32, 64);
    if (lane < 16) wred[wid][nf * 16 + lc] = cs[nf];
  }
  __syncthreads();
  if (tid < 64) {
    float w4 = wred[0][tid] + wred[1][tid] + wred[2][tid] + wred[3][tid];
    int slot = ((b * 12 + head) * 64 + nseg * 16 + qblk);
    partial[slot * 64 + tid] = w4;
  }
}

// div[b*768 + h*64 + d] = sum over this head's (nsegs*16) block partials
__global__ __launch_bounds__(256) void colsum2_kernel(const float* __restrict__ partial,
                                                      float* __restrict__ divbuf) {
  int i = blockIdx.x * 256 + threadIdx.x;  // 0..1535
  int b = i / 768, e = i % 768;
  int h = e >> 6, d = e & 63;
  int g = h >> 2;
  int nslots = 64 >> g;
  const float* src = partial + (size_t)((b * 12 + h) * 64) * 64 + d;
  float sacc = 0.f;
  for (int c = 0; c < nslots; ++c) sacc += src[c * 64];
  divbuf[i] = sacc;
}

// LayerNorm, wave-per-row: fp16 in/out, fuses /(div*3) + written-slot mask.
__global__ __launch_bounds__(256) void ln_kernel(const _Float16* __restrict__ Xh,
                                                 _Float16* __restrict__ Xln,
                                                 const float* __restrict__ divbuf,
                                                 const float* __restrict__ ln_w,
                                                 const float* __restrict__ ln_b) {
  int wid = threadIdx.x >> 6, lane = threadIdx.x & 63;
  int row = blockIdx.x * 4 + wid;
  int b = row >> 13, pos = row & 8191;
  float x[12];
  float s1 = 0.f, s2 = 0.f;
#pragma unroll
  for (int j = 0; j < 12; ++j) {
    int e = lane + 64 * j;
    int g = j >> 2;
    bool wr = (g == 0) || (g == 1 && (pos & 1) == 1) || (g == 2 && (pos & 3) == 2);
    float v = 0.f;
    if (wr) v = (float)Xh[(size_t)row * 768 + e] / (divbuf[b * 768 + e] * 3.0f);
    x[j] = v;
    s1 += v;
    s2 += v * v;
  }
#pragma unroll
  for (int msk = 1; msk < 64; msk <<= 1) {
    s1 += __shfl_xor(s1, msk, 64);
    s2 += __shfl_xor(s2, msk, 64);
  }
  float mean = s1 * (1.0f / 768.0f);
  float var = s2 * (1.0f / 768.0f) - mean * mean;
  float inv = rsqrtf(var + 1e-5f);
#pragma unroll
  for (int j = 0; j < 12; ++j) {
    int e = lane + 64 * j;
    Xln[(size_t)row * 768 + e] = (_Float16)((x[j] - mean) * inv * ln_w[e] + ln_b[e]);
  }
}

extern "C" void kernel_launch(void* const* d_in, const int* in_sizes, int n_in,
                              void* d_out, int out_size, void* d_ws, size_t ws_size,
                              hipStream_t stream) {
  const float* query = (const float*)d_in[0];
  const float* key   = (const float*)d_in[1];
  const float* value = (const float*)d_in[2];
  const float* Wq = (const float*)d_in[3];
  const float* bq = (const float*)d_in[4];
  const float* Wk = (const float*)d_in[5];
  const float* bk = (const float*)d_in[6];
  const float* Wv = (const float*)d_in[7];
  const float* bv = (const float*)d_in[8];
  const float* Wo = (const float*)d_in[9];
  const float* bo = (const float*)d_in[10];
  const float* ln_w = (const float*)d_in[11];
  const float* ln_b = (const float*)d_in[12];

  char* ws = (char*)d_ws;
  _Float16* Wsh = (_Float16*)ws; ws += (size_t)4 * 589824 * 2;
  _Float16* Wsl = (_Float16*)ws; ws += (size_t)4 * 589824 * 2;
  _Float16* Qhb = (_Float16*)ws; ws += (size_t)16384 * 768 * 2;
  _Float16* Qlb = (_Float16*)ws; ws += (size_t)16384 * 768 * 2;
  _Float16* Khb = (_Float16*)ws; ws += (size_t)16384 * 768 * 2;
  _Float16* Klb = (_Float16*)ws; ws += (size_t)16384 * 768 * 2;
  _Float16* Vth = (_Float16*)ws; ws += (size_t)7340032 * 2;
  _Float16* Vtl = (_Float16*)ws; ws += (size_t)7340032 * 2;
  _Float16* Xh  = (_Float16*)ws; ws += (size_t)16384 * 768 * 2;
  _Float16* Xln = (_Float16*)ws; ws += (size_t)16384 * 768 * 2;
  float* partial = (float*)ws; ws += (size_t)24 * 64 * 64 * 4;
  float* divbuf = (float*)ws; ws += 2 * 768 * 4;

  wsplit4_kernel<<<dim3(2304, 4), 256, 0, stream>>>(Wq, Wk, Wv, Wo, Wsh, Wsl);

  gemm3b_kernel<<<2304, 512, 0, stream>>>(
      query, key, value, Wsh, Wsl, bq, bk, bv,
      Qhb, Qlb, Khb, Klb, Vth, Vtl);

  attn_kernel<<<896, 256, 0, stream>>>(Qhb, Qlb, Khb, Klb, Vth, Vtl, Xh, partial);

  colsum2_kernel<<<6, 256, 0, stream>>>(partial, divbuf);
  ln_kernel<<<4096, 256, 0, stream>>>(Xh, Xln, divbuf, ln_w, ln_b);

  gemm1_kernel<<<768, 256, 0, stream>>>(Xln, Wsh + 3 * 589824, bo, (float*)d_out);
}